// Round 1
// baseline (474.577 us; speedup 1.0000x reference)
//
#include <hip/hip_runtime.h>

#define NT 64
#define NB 8192
#define NS 32
#define NF 16
#define DT 0.05f
#define FP_ITERS 8
#define GROUPS_PER_BLOCK 8

__global__ __launch_bounds__(256) void rnes_kernel(
    const float* __restrict__ y0,
    const float* __restrict__ forces,
    const float* __restrict__ W,
    const float* __restrict__ U,
    const float* __restrict__ bias,
    float* __restrict__ out)
{
    const int lane  = threadIdx.x & 31;   // state index j
    const int grp   = threadIdx.x >> 5;   // group within block
    const int batch = blockIdx.x * GROUPS_PER_BLOCK + grp;

    __shared__ float y_sh[GROUPS_PER_BLOCK][NS];
    __shared__ float u_sh[GROUPS_PER_BLOCK][NF];

    // --- per-lane constant rows of W and U in registers ---
    float Wrow[NS];
#pragma unroll
    for (int i = 0; i < NS / 4; ++i) {
        float4 w4 = ((const float4*)(W + lane * NS))[i];
        Wrow[4*i+0] = w4.x; Wrow[4*i+1] = w4.y;
        Wrow[4*i+2] = w4.z; Wrow[4*i+3] = w4.w;
    }
    float Urow[NF];
#pragma unroll
    for (int i = 0; i < NF / 4; ++i) {
        float4 u4 = ((const float4*)(U + lane * NF))[i];
        Urow[4*i+0] = u4.x; Urow[4*i+1] = u4.y;
        Urow[4*i+2] = u4.z; Urow[4*i+3] = u4.w;
    }
    const float bj = bias[lane];

    float y_prev = y0[batch * NS + lane];
    // out[0] = y0
    out[batch * NS + lane] = y_prev;

    for (int k = 1; k < NT; ++k) {
        // stage forces[k][batch][:] into LDS
        if (lane < NF)
            u_sh[grp][lane] = forces[((size_t)k * NB + batch) * NF + lane];
        __syncthreads();

        float fu = bj;
#pragma unroll
        for (int i = 0; i < NF / 4; ++i) {
            float4 u4 = ((const float4*)u_sh[grp])[i];
            fu += Urow[4*i+0]*u4.x + Urow[4*i+1]*u4.y
                + Urow[4*i+2]*u4.z + Urow[4*i+3]*u4.w;
        }

        // warm start: y = y_prev
        float yj = y_prev;
        y_sh[grp][lane] = yj;
        __syncthreads();

#pragma unroll
        for (int it = 0; it < FP_ITERS; ++it) {
            float z = fu;
#pragma unroll
            for (int i = 0; i < NS / 4; ++i) {
                float4 yv = ((const float4*)y_sh[grp])[i];   // broadcast read
                z += Wrow[4*i+0]*yv.x + Wrow[4*i+1]*yv.y
                   + Wrow[4*i+2]*yv.z + Wrow[4*i+3]*yv.w;
            }
            yj = y_prev + DT * tanhf(z);
            __syncthreads();          // WAR: everyone done reading y_sh
            y_sh[grp][lane] = yj;
            __syncthreads();          // RAW: new y visible to all
        }

        y_prev = yj;
        out[((size_t)k * NB + batch) * NS + lane] = yj;
    }
}

extern "C" void kernel_launch(void* const* d_in, const int* in_sizes, int n_in,
                              void* d_out, int out_size, void* d_ws, size_t ws_size,
                              hipStream_t stream) {
    const float* y0     = (const float*)d_in[0];
    const float* forces = (const float*)d_in[1];
    const float* W      = (const float*)d_in[2];
    const float* U      = (const float*)d_in[3];
    const float* b      = (const float*)d_in[4];
    float* out = (float*)d_out;

    dim3 grid(NB / GROUPS_PER_BLOCK);
    dim3 block(256);
    rnes_kernel<<<grid, block, 0, stream>>>(y0, forces, W, U, b, out);
}

// Round 2
// 216.527 us; speedup vs baseline: 2.1918x; 2.1918x over previous
//
#include <hip/hip_runtime.h>

#define NT 64
#define NB 8192
#define NS 32
#define NF 16
#define DT 0.05f
#define FP_ITERS 6
#define GROUPS_PER_BLOCK 8   // 256 threads = 4 waves; 2 groups (batches) per wave

// tanh(x) = 1 - 2/(exp(2x)+1); saturates correctly for |x| large (inf-safe).
__device__ __forceinline__ float tanh_fast(float x) {
    float e = __expf(2.0f * x);                 // v_mul + v_exp_f32
    float r = __builtin_amdgcn_rcpf(e + 1.0f);  // raw v_rcp_f32, no refine
    return fmaf(-2.0f, r, 1.0f);
}

__global__ __launch_bounds__(256) void rnes_kernel(
    const float* __restrict__ y0,
    const float* __restrict__ forces,
    const float* __restrict__ W,
    const float* __restrict__ U,
    const float* __restrict__ bias,
    float* __restrict__ out)
{
    const int lane  = threadIdx.x & 31;   // state index j
    const int grp   = threadIdx.x >> 5;   // group (batch) within block
    const int batch = blockIdx.x * GROUPS_PER_BLOCK + grp;

    __shared__ float y_sh[GROUPS_PER_BLOCK][NS];

    // --- per-lane constant rows of W and U in registers ---
    float Wrow[NS];
#pragma unroll
    for (int i = 0; i < NS / 4; ++i) {
        float4 w4 = ((const float4*)(W + lane * NS))[i];
        Wrow[4*i+0] = w4.x; Wrow[4*i+1] = w4.y;
        Wrow[4*i+2] = w4.z; Wrow[4*i+3] = w4.w;
    }
    float Urow[NF];
#pragma unroll
    for (int i = 0; i < NF / 4; ++i) {
        float4 u4 = ((const float4*)(U + lane * NF))[i];
        Urow[4*i+0] = u4.x; Urow[4*i+1] = u4.y;
        Urow[4*i+2] = u4.z; Urow[4*i+3] = u4.w;
    }
    const float bj = bias[lane];

    float y_prev = y0[batch * NS + lane];
    out[batch * NS + lane] = y_prev;            // result[0] = y0

    // prefetch forces for step 1 (all 32 lanes of a group broadcast-load 64 B)
    const float4* fp1 = (const float4*)(forces + ((size_t)1 * NB + batch) * NF);
    float4 u0 = fp1[0], u1 = fp1[1], u2 = fp1[2], u3 = fp1[3];

    for (int k = 1; k < NT; ++k) {
        // fu = U u_k + b (per-lane dot with prefetched registers)
        float fu = bj;
        fu = fmaf(Urow[ 0], u0.x, fu); fu = fmaf(Urow[ 1], u0.y, fu);
        fu = fmaf(Urow[ 2], u0.z, fu); fu = fmaf(Urow[ 3], u0.w, fu);
        fu = fmaf(Urow[ 4], u1.x, fu); fu = fmaf(Urow[ 5], u1.y, fu);
        fu = fmaf(Urow[ 6], u1.z, fu); fu = fmaf(Urow[ 7], u1.w, fu);
        fu = fmaf(Urow[ 8], u2.x, fu); fu = fmaf(Urow[ 9], u2.y, fu);
        fu = fmaf(Urow[10], u2.z, fu); fu = fmaf(Urow[11], u2.w, fu);
        fu = fmaf(Urow[12], u3.x, fu); fu = fmaf(Urow[13], u3.y, fu);
        fu = fmaf(Urow[14], u3.z, fu); fu = fmaf(Urow[15], u3.w, fu);

        // prefetch next step's forces while iterating (clamp to avoid OOB)
        {
            int kn = (k + 1 < NT) ? (k + 1) : (NT - 1);
            const float4* fpn = (const float4*)(forces + ((size_t)kn * NB + batch) * NF);
            u0 = fpn[0]; u1 = fpn[1]; u2 = fpn[2]; u3 = fpn[3];
        }

        // publish warm start y = y_prev (wave-synchronous: no s_barrier needed,
        // groups are contained in a single lockstep wave; DS pipe is in-order)
        y_sh[grp][lane] = y_prev;
        asm volatile("s_waitcnt lgkmcnt(0)" ::: "memory");

        float yj = y_prev;
#pragma unroll
        for (int it = 0; it < FP_ITERS; ++it) {
            float z = fu;
#pragma unroll
            for (int i = 0; i < NS / 4; ++i) {
                float4 yv = ((const float4*)y_sh[grp])[i];   // broadcast read
                z = fmaf(Wrow[4*i+0], yv.x, z);
                z = fmaf(Wrow[4*i+1], yv.y, z);
                z = fmaf(Wrow[4*i+2], yv.z, z);
                z = fmaf(Wrow[4*i+3], yv.w, z);
            }
            yj = fmaf(DT, tanh_fast(z), y_prev);
            if (it != FP_ITERS - 1) {
                // reads above are ordered before this write by the DS pipe
                // (in-order per wave) + the asm memory clobbers.
                asm volatile("" ::: "memory");
                y_sh[grp][lane] = yj;
                asm volatile("s_waitcnt lgkmcnt(0)" ::: "memory");
            }
        }

        y_prev = yj;
        out[((size_t)k * NB + batch) * NS + lane] = yj;
    }
}

extern "C" void kernel_launch(void* const* d_in, const int* in_sizes, int n_in,
                              void* d_out, int out_size, void* d_ws, size_t ws_size,
                              hipStream_t stream) {
    const float* y0     = (const float*)d_in[0];
    const float* forces = (const float*)d_in[1];
    const float* W      = (const float*)d_in[2];
    const float* U      = (const float*)d_in[3];
    const float* b      = (const float*)d_in[4];
    float* out = (float*)d_out;

    dim3 grid(NB / GROUPS_PER_BLOCK);
    dim3 block(256);
    rnes_kernel<<<grid, block, 0, stream>>>(y0, forces, W, U, b, out);
}

// Round 3
// 186.959 us; speedup vs baseline: 2.5384x; 1.1582x over previous
//
#include <hip/hip_runtime.h>

#define NT 64
#define NB 8192
#define NS 32
#define NF 16
#define DT 0.05f
#define FP_ITERS 5
#define LSTRIDE 40   // shorts per batch row (32 states + 8 pad) = 80 B, 16B-aligned

typedef float  f32x4  __attribute__((ext_vector_type(4)));
typedef short  bf16x8 __attribute__((ext_vector_type(8)));

#define MFMA16 __builtin_amdgcn_mfma_f32_16x16x32_bf16

union frag_u { unsigned u[4]; bf16x8 v; };

// pack {lo16 = top16(a), hi16 = top16(b)}  (truncation-split to bf16 pair)
__device__ __forceinline__ unsigned pack_hi16(float a, float b) {
    return __builtin_amdgcn_perm(__float_as_uint(b), __float_as_uint(a), 0x07060302u);
}
__device__ __forceinline__ float trunc_bf(float x) {
    return __uint_as_float(__float_as_uint(x) & 0xffff0000u);
}
__device__ __forceinline__ float tanh_fast(float x) {
    float e = __expf(2.0f * x);
    float r = __builtin_amdgcn_rcpf(e + 1.0f);
    return fmaf(-2.0f, r, 1.0f);
}
// split 8 fp32 into bf16-hi and bf16-lo fragments (truncation split: exact sum to ~17 bits)
__device__ __forceinline__ void split8(const float* w, frag_u& hi, frag_u& lo) {
    float l[8];
#pragma unroll
    for (int e = 0; e < 8; ++e) l[e] = w[e] - trunc_bf(w[e]);
    hi.u[0] = pack_hi16(w[0], w[1]); hi.u[1] = pack_hi16(w[2], w[3]);
    hi.u[2] = pack_hi16(w[4], w[5]); hi.u[3] = pack_hi16(w[6], w[7]);
    lo.u[0] = pack_hi16(l[0], l[1]); lo.u[1] = pack_hi16(l[2], l[3]);
    lo.u[2] = pack_hi16(l[4], l[5]); lo.u[3] = pack_hi16(l[6], l[7]);
}

__global__ __launch_bounds__(64) void rnes_kernel(
    const float* __restrict__ y0,
    const float* __restrict__ forces,
    const float* __restrict__ W,
    const float* __restrict__ U,
    const float* __restrict__ bias,
    float* __restrict__ out)
{
    const int lane  = threadIdx.x;      // 0..63 (one wave per block)
    const int col   = lane & 15;        // batch within tile == MFMA col
    const int h     = lane >> 4;        // quad 0..3
    const int batch = blockIdx.x * 16 + col;

    __shared__ __align__(16) short Yhi[16 * LSTRIDE];
    __shared__ __align__(16) short Ylo[16 * LSTRIDE];

    // ---- static A-frags: W (two 16-state tiles), hi/lo split ----
    // A[m=16T+col][k=8h+e]  (row-major W: 8 consecutive cols)
    frag_u Whi[2], Wlo[2];
#pragma unroll
    for (int T = 0; T < 2; ++T) {
        const float* wr = W + (16*T + col) * NS + 8*h;
        float w[8];
        f32x4 wa = *(const f32x4*)(wr);
        f32x4 wb = *(const f32x4*)(wr + 4);
#pragma unroll
        for (int e = 0; e < 4; ++e) { w[e] = wa[e]; w[4+e] = wb[e]; }
        split8(w, Whi[T], Wlo[T]);
    }

    // ---- static A-frags: U padded to K=32 with zeros (h>=2 -> k>=16 -> 0) ----
    frag_u Uhi[2], Ulo[2];
#pragma unroll
    for (int T = 0; T < 2; ++T) {
        if (h < 2) {
            const float* ur = U + (16*T + col) * NF + 8*h;
            float u[8];
            f32x4 ua = *(const f32x4*)(ur);
            f32x4 ub = *(const f32x4*)(ur + 4);
#pragma unroll
            for (int e = 0; e < 4; ++e) { u[e] = ua[e]; u[4+e] = ub[e]; }
            split8(u, Uhi[T], Ulo[T]);
        } else {
#pragma unroll
            for (int r = 0; r < 4; ++r) { Uhi[T].u[r] = 0u; Ulo[T].u[r] = 0u; }
        }
    }

    // bias in C-layout: value b[16T+4h+r], same for all batch cols
    f32x4 bfr[2];
    bfr[0] = *(const f32x4*)(bias + 4*h);
    bfr[1] = *(const f32x4*)(bias + 16 + 4*h);

    // y_prev in C-layout (states 16T+4h+0..3 of this lane's batch)
    f32x4 yp0 = *(const f32x4*)(y0 + (size_t)batch * NS + 4*h);
    f32x4 yp1 = *(const f32x4*)(y0 + (size_t)batch * NS + 16 + 4*h);
    *(f32x4*)(out + (size_t)batch * NS + 4*h)      = yp0;   // out[0] = y0
    *(f32x4*)(out + (size_t)batch * NS + 16 + 4*h) = yp1;

    // prefetch forces for k=1 (B-frag needs forces f = 8h..8h+7; h>=2 lanes are
    // dead weight (A is zero there) — load h&1 region to stay in-bounds/finite)
    const size_t fstep = (size_t)NB * NF;
    const float* fbase = forces + (size_t)batch * NF + 8*(h & 1);
    f32x4 uc0 = *(const f32x4*)(fbase + fstep);
    f32x4 uc1 = *(const f32x4*)(fbase + fstep + 4);

    for (int k = 1; k < NT; ++k) {
        // ---- fu = U u + b via 3-term split MFMA ----
        float uf[8];
#pragma unroll
        for (int e = 0; e < 4; ++e) { uf[e] = uc0[e]; uf[4+e] = uc1[e]; }
        frag_u uH, uL;
        split8(uf, uH, uL);
        f32x4 fu0 = MFMA16(Uhi[0].v, uH.v, bfr[0], 0, 0, 0);
        fu0 = MFMA16(Uhi[0].v, uL.v, fu0, 0, 0, 0);
        fu0 = MFMA16(Ulo[0].v, uH.v, fu0, 0, 0, 0);
        f32x4 fu1 = MFMA16(Uhi[1].v, uH.v, bfr[1], 0, 0, 0);
        fu1 = MFMA16(Uhi[1].v, uL.v, fu1, 0, 0, 0);
        fu1 = MFMA16(Ulo[1].v, uH.v, fu1, 0, 0, 0);

        // prefetch next step's forces (hidden behind the iteration loop)
        {
            int kn = (k + 1 < NT) ? (k + 1) : (NT - 1);
            uc0 = *(const f32x4*)(fbase + (size_t)kn * fstep);
            uc1 = *(const f32x4*)(fbase + (size_t)kn * fstep + 4);
        }

        // ---- fixed-point iterations, warm start y = y_prev ----
        f32x4 ya = yp0, yb = yp1;
#pragma unroll
        for (int it = 0; it < FP_ITERS; ++it) {
            // split y (C-layout regs) to bf16 hi/lo and publish to LDS [batch][state]
            float la0 = ya[0]-trunc_bf(ya[0]), la1 = ya[1]-trunc_bf(ya[1]);
            float la2 = ya[2]-trunc_bf(ya[2]), la3 = ya[3]-trunc_bf(ya[3]);
            float lb0 = yb[0]-trunc_bf(yb[0]), lb1 = yb[1]-trunc_bf(yb[1]);
            float lb2 = yb[2]-trunc_bf(yb[2]), lb3 = yb[3]-trunc_bf(yb[3]);
            unsigned long long wha = (unsigned long long)pack_hi16(ya[0], ya[1])
                                   | ((unsigned long long)pack_hi16(ya[2], ya[3]) << 32);
            unsigned long long whb = (unsigned long long)pack_hi16(yb[0], yb[1])
                                   | ((unsigned long long)pack_hi16(yb[2], yb[3]) << 32);
            unsigned long long wla = (unsigned long long)pack_hi16(la0, la1)
                                   | ((unsigned long long)pack_hi16(la2, la3) << 32);
            unsigned long long wlb = (unsigned long long)pack_hi16(lb0, lb1)
                                   | ((unsigned long long)pack_hi16(lb2, lb3) << 32);
            *(unsigned long long*)(Yhi + col*LSTRIDE + 4*h)      = wha;  // states 4h+0..3
            *(unsigned long long*)(Yhi + col*LSTRIDE + 16 + 4*h) = whb;  // states 16+4h+0..3
            *(unsigned long long*)(Ylo + col*LSTRIDE + 4*h)      = wla;
            *(unsigned long long*)(Ylo + col*LSTRIDE + 16 + 4*h) = wlb;
            asm volatile("" ::: "memory");   // pin order; DS pipe is in-order per wave
            // B-frag read: y[k = 8h+e][batch = col]
            bf16x8 byh = *(const bf16x8*)(Yhi + col*LSTRIDE + 8*h);
            bf16x8 byl = *(const bf16x8*)(Ylo + col*LSTRIDE + 8*h);

            f32x4 z0 = MFMA16(Whi[0].v, byh, fu0, 0, 0, 0);
            z0 = MFMA16(Whi[0].v, byl, z0, 0, 0, 0);
            z0 = MFMA16(Wlo[0].v, byh, z0, 0, 0, 0);
            f32x4 z1 = MFMA16(Whi[1].v, byh, fu1, 0, 0, 0);
            z1 = MFMA16(Whi[1].v, byl, z1, 0, 0, 0);
            z1 = MFMA16(Wlo[1].v, byh, z1, 0, 0, 0);

#pragma unroll
            for (int r = 0; r < 4; ++r) {
                ya[r] = fmaf(DT, tanh_fast(z0[r]), yp0[r]);
                yb[r] = fmaf(DT, tanh_fast(z1[r]), yp1[r]);
            }
            asm volatile("" ::: "memory");
        }

        yp0 = ya; yp1 = yb;
        float* o = out + ((size_t)k * NB + batch) * NS;
        *(f32x4*)(o + 4*h)      = yp0;
        *(f32x4*)(o + 16 + 4*h) = yp1;
    }
}

extern "C" void kernel_launch(void* const* d_in, const int* in_sizes, int n_in,
                              void* d_out, int out_size, void* d_ws, size_t ws_size,
                              hipStream_t stream) {
    const float* y0     = (const float*)d_in[0];
    const float* forces = (const float*)d_in[1];
    const float* W      = (const float*)d_in[2];
    const float* U      = (const float*)d_in[3];
    const float* b      = (const float*)d_in[4];
    float* out = (float*)d_out;

    dim3 grid(NB / 16);   // 512 blocks, one 16-batch tile per wave
    dim3 block(64);
    rnes_kernel<<<grid, block, 0, stream>>>(y0, forces, W, U, b, out);
}

// Round 4
// 172.230 us; speedup vs baseline: 2.7555x; 1.0855x over previous
//
#include <hip/hip_runtime.h>

#define NT 64
#define NB 8192
#define NS 32
#define NF 16
#define DT 0.05f
#define FP_ITERS 4
#define YSTR 36   // floats per batch row in Y LDS (32 + 4 pad) = 144 B, 16B-aligned
#define USTR 20   // floats per batch row in U LDS (16 + 4 pad) = 80 B, 16B-aligned

typedef float f32x2 __attribute__((ext_vector_type(2)));
typedef float f32x4 __attribute__((ext_vector_type(4)));

__device__ __forceinline__ float tanh_fast(float x) {
    float e = __expf(2.0f * x);                 // v_mul + v_exp_f32
    float r = __builtin_amdgcn_rcpf(e + 1.0f);  // raw v_rcp_f32
    return fmaf(-2.0f, r, 1.0f);
}

// Lane map: lane = b*16 + p;  b = batch within wave tile [0,4), p = state pair
// [0,16) -> states 2p, 2p+1.  Each wave owns 4 batches; waves are independent
// (no inter-wave sync; LDS regions disjoint per wave; intra-wave lockstep makes
// the LDS y-exchange barrier-free — validated in R2/R3).
__global__ __launch_bounds__(256) void rnes_kernel(
    const float* __restrict__ y0,
    const float* __restrict__ forces,
    const float* __restrict__ W,
    const float* __restrict__ U,
    const float* __restrict__ bias,
    float* __restrict__ out)
{
    const int lane = threadIdx.x & 63;
    const int wv   = threadIdx.x >> 6;
    const int b    = lane >> 4;
    const int p    = lane & 15;
    const int batch = blockIdx.x * 16 + wv * 4 + b;

    __shared__ __align__(16) float Ysh[4][4 * YSTR];
    __shared__ __align__(16) float Ush[4][4 * USTR];
    float* Yw = Ysh[wv] + b * YSTR;
    float* Uw = Ush[wv] + b * USTR;

    // W2[k] = (W[2p][k], W[2p+1][k]) — 64 VGPRs
    f32x2 W2[NS];
#pragma unroll
    for (int k = 0; k < NS; k += 4) {
        f32x4 r0 = *(const f32x4*)(W + (2*p)   * NS + k);
        f32x4 r1 = *(const f32x4*)(W + (2*p+1) * NS + k);
#pragma unroll
        for (int e = 0; e < 4; ++e) W2[k+e] = (f32x2){r0[e], r1[e]};
    }
    // U2[f] = (U[2p][f], U[2p+1][f]) — 32 VGPRs
    f32x2 U2[NF];
#pragma unroll
    for (int f = 0; f < NF; f += 4) {
        f32x4 r0 = *(const f32x4*)(U + (2*p)   * NF + f);
        f32x4 r1 = *(const f32x4*)(U + (2*p+1) * NF + f);
#pragma unroll
        for (int e = 0; e < 4; ++e) U2[f+e] = (f32x2){r0[e], r1[e]};
    }
    const f32x2 b2 = *(const f32x2*)(bias + 2*p);

    // y_prev (this lane's 2 states), out[0] = y0, seed Y LDS
    f32x2 yp = *(const f32x2*)(y0 + (size_t)batch * NS + 2*p);
    *(f32x2*)(out + (size_t)batch * NS + 2*p) = yp;
    *(f32x2*)(Yw + 2*p) = yp;
    asm volatile("" ::: "memory");

    // prefetch forces for k=1: lane (b,p) loads forces[k][batch][p]
    float fpre = forces[((size_t)1 * NB + batch) * NF + p];

    for (int k = 1; k < NT; ++k) {
        // stage forces (transpose-free: [b][f] rows, broadcast-read below)
        Uw[p] = fpre;
        asm volatile("" ::: "memory");

        // fu = U u + b   (4 broadcast float4 reads + 16 pk_fma)
        f32x2 fu = b2;
#pragma unroll
        for (int f = 0; f < NF; f += 4) {
            f32x4 u4 = *(const f32x4*)(Uw + f);
            fu = U2[f+0] * u4[0] + fu;
            fu = U2[f+1] * u4[1] + fu;
            fu = U2[f+2] * u4[2] + fu;
            fu = U2[f+3] * u4[3] + fu;
        }

        // prefetch next step's forces (hidden behind the iteration loop)
        {
            int kn = (k + 1 < NT) ? (k + 1) : (NT - 1);
            fpre = forces[((size_t)kn * NB + batch) * NF + p];
        }

        // fixed-point iterations; Y LDS holds y_prev on entry
        f32x2 y = yp;
#pragma unroll
        for (int it = 0; it < FP_ITERS; ++it) {
            f32x2 z = fu;
#pragma unroll
            for (int i = 0; i < NS; i += 4) {
                f32x4 yv = *(const f32x4*)(Yw + i);   // broadcast within b-group
                z = W2[i+0] * yv[0] + z;
                z = W2[i+1] * yv[1] + z;
                z = W2[i+2] * yv[2] + z;
                z = W2[i+3] * yv[3] + z;
            }
            float t0 = tanh_fast(z[0]);
            float t1 = tanh_fast(z[1]);
            y[0] = fmaf(DT, t0, yp[0]);
            y[1] = fmaf(DT, t1, yp[1]);
            // wave-lockstep: all lanes' reads above issued before this write;
            // DS pipe is in-order; clobbers pin compiler ordering.
            asm volatile("" ::: "memory");
            *(f32x2*)(Yw + 2*p) = y;   // also seeds next step's warm start
            asm volatile("" ::: "memory");
        }

        yp = y;
        *(f32x2*)(out + ((size_t)k * NB + batch) * NS + 2*p) = yp;
    }
}

extern "C" void kernel_launch(void* const* d_in, const int* in_sizes, int n_in,
                              void* d_out, int out_size, void* d_ws, size_t ws_size,
                              hipStream_t stream) {
    const float* y0     = (const float*)d_in[0];
    const float* forces = (const float*)d_in[1];
    const float* W      = (const float*)d_in[2];
    const float* U      = (const float*)d_in[3];
    const float* b      = (const float*)d_in[4];
    float* out = (float*)d_out;

    dim3 grid(NB / 16);   // 512 blocks × 4 waves, 4 batches per wave
    dim3 block(256);
    rnes_kernel<<<grid, block, 0, stream>>>(y0, forces, W, U, b, out);
}